// Round 3
// baseline (497.486 us; speedup 1.0000x reference)
//
#include <hip/hip_runtime.h>

typedef unsigned short u16;
typedef __attribute__((ext_vector_type(8))) __bf16 bf16x8;
typedef __attribute__((ext_vector_type(8))) short short8;
typedef __attribute__((ext_vector_type(4))) short short4v;
typedef __attribute__((ext_vector_type(4))) float floatx4;

__device__ __forceinline__ u16 f2bf(float f){
  unsigned int x = __float_as_uint(f);
  unsigned int r = (x + 0x7fffu + ((x >> 16) & 1u)) >> 16;  // RTNE
  return (u16)r;
}

// async 16B global->LDS copy; lds base must be wave-uniform (HW: base + lane*16)
#define GLL(g, l) __builtin_amdgcn_global_load_lds( \
    (const __attribute__((address_space(1))) void*)(g), \
    (__attribute__((address_space(3))) void*)(l), 16, 0, 0)

// ============================ PREP PASS =====================================
// blocks 0..1023: x[b][ci][t][y][zw] fp32 -> xp[b][t][y][zw][ci] bf16,
//   16B chunks XOR-placed: chunk position p holds ci-oct (p ^ (zw&7)).
//   LDS-staged transpose (round-1): float4 coalesced reads, coalesced b128 stores.
// blocks 1024..2319: weight fp32 -> wp[tap][kc][co][ci32] bf16 (coalesced reads).
__global__ void prep_kernel(const float* __restrict__ x, const float* __restrict__ w,
                            u16* __restrict__ xp, u16* __restrict__ wp){
  __shared__ __attribute__((aligned(16))) u16 I[16384];  // 32 KB: [ci][granule] swizzled
  const int bx = blockIdx.x;
  const int tid = threadIdx.x;
  if (bx < 1024){
    const int y = bx & 15, t = (bx >> 4) & 15, b = bx >> 8;
    const int l  = tid & 63;   // lane
    const int wv = tid >> 6;   // wave
    const float* xb = x + (size_t)b*64*65536 + t*4096 + y*256;

    // ---- Phase A: read + convert + swizzled LDS write ----
#pragma unroll
    for (int j = 0; j < 16; ++j){
      const int ci = j*4 + wv;
      const float4 f = *(const float4*)(xb + (size_t)ci*65536 + l*4);
      const int o  = ci >> 3;
      const int gp = l ^ o ^ ((o & 1) << 3);     // granule swizzle (bijective per ci)
      short4v hv;
      hv[0] = (short)f2bf(f.x);
      hv[1] = (short)f2bf(f.y);
      hv[2] = (short)f2bf(f.z);
      hv[3] = (short)f2bf(f.w);
      *(short4v*)(I + ci*256 + gp*4) = hv;       // b64, 8B aligned
    }
    __syncthreads();

    // ---- Phase B: gather + coalesced b128 global store ----
    const int p  = tid & 7;
    const int r0 = tid >> 3;
    u16* dst = xp + (size_t)bx*16384;
#pragma unroll
    for (int it = 0; it < 8; ++it){
      const int zw = it*32 + r0;
      const int o  = p ^ (zw & 7);
      const int g  = zw >> 2;
      const int gp = g ^ o ^ ((o & 1) << 3);
      const int base = gp*4 + (zw & 3);
      short8 vv;
#pragma unroll
      for (int m = 0; m < 8; ++m)
        vv[m] = (short)I[(o*8 + m)*256 + base];
      *(short8*)(dst + it*2048 + tid*8) = vv;    // 1 KB contiguous per wave-instr
    }
  } else {
    int idx = (bx - 1024)*256 + tid;   // linear over w input (coalesced)
    if (idx < 81*64*64){
      int r  = idx;
      int dw = r % 3; r /= 3;
      int dz = r % 3; r /= 3;
      int dy = r % 3; r /= 3;
      int ci = r & 63; r >>= 6;
      int co = r & 63; r >>= 6;
      int dt = r;
      int tap = ((dt*3 + dy)*3 + dz)*3 + dw;
      int kc = ci >> 5, ci32 = ci & 31;
      wp[tap*4096 + kc*2048 + co*32 + ci32] = f2bf(w[idx]);
    }
  }
}

// ============================ MAIN KERNEL ===================================
// v5: occupancy-first restructure.
//  - a_lds ELIMINATED: wp is 663 KB (L2-resident); A-fragments are read with
//    plain global b128 loads. No barrier forces their drain -> compiler
//    pipelines them across the unrolled (dw,kc) groups under vmcnt.
//  - LDS = x plane only (32 KB) -> 4 blocks/CU (__launch_bounds__(256,4)),
//    4 independent waves/SIMD: when one block sits at its restage barrier,
//    three others keep the MFMA pipe fed.
//  - barriers 34 -> 18 per block (x restage only).
__global__ __launch_bounds__(256, 4) void conv4d_mfma_v5(
    const u16* __restrict__ xp, const u16* __restrict__ wp,
    const float* __restrict__ bias, float* __restrict__ out)
{
  __shared__ __attribute__((aligned(16))) u16 x_lds[16384];     // [zw][ci], XOR chunks

  // XCD-aware swizzle: XCD c = bx&7 owns (b = c>>1, y-half = c&1) — its 9x
  // re-reads of xp planes stay in its own L2.
  const int bx = blockIdx.x;
  const int c = bx & 7, j = bx >> 3;
  const int b = c >> 1, t = j >> 3, y = (c & 1)*8 + (j & 7);

  const int tid  = threadIdx.x;
  const int lane = tid & 63;
  const int wv   = tid >> 6;
  const int wl   = lane & 15;   // B: n (w-pos); A: m (co row within 16-tile)
  const int q    = lane >> 4;   // k-octet selector; D: co = quad*4+reg

  floatx4 acc[4][4];
#pragma unroll
  for (int zi = 0; zi < 4; ++zi)
#pragma unroll
    for (int mi = 0; mi < 4; ++mi)
      acc[zi][mi] = (floatx4)0.0f;

  // per-thread A base: wp + co(wl)-row + ci-octet(q); dw/kc/mi offsets are
  // compile-time constants folded into the load offsets.
  const u16* wpt = wp + wl*32 + q*8;

  for (int dtdy = 0; dtdy < 9; ++dtdy){
    const int dt = dtdy / 3, dy = dtdy % 3;
    const int tt = (t + dt + 15) & 15;
    const int yy = (y + dy + 15) & 15;
    const u16* plane = xp + (size_t)(((b*16 + tt)*16) + yy) * 16384;

    if (dtdy) __syncthreads();            // everyone done reading previous plane
#pragma unroll
    for (int i = 0; i < 8; ++i)
      GLL(plane + wv*4096 + i*512 + lane*8, x_lds + wv*4096 + i*512);
    __syncthreads();                      // drain: plane ready

#pragma unroll
    for (int dz = 0; dz < 3; ++dz){
      const u16* ab = wpt + (size_t)(dtdy*9 + dz*3) * 4096;   // slab base (3 taps)
#pragma unroll
      for (int dw = 0; dw < 3; ++dw){
        const int ww = (wl + dw + 15) & 15;
        const int wx = ww & 7;
#pragma unroll
        for (int kc = 0; kc < 2; ++kc){
          bf16x8 af[4];
#pragma unroll
          for (int mi = 0; mi < 4; ++mi)
            af[mi] = *(const bf16x8*)(ab + dw*4096 + kc*2048 + mi*512);  // global, L2-hot
          const int chunk = ((kc*4 + q) ^ wx)*8;
#pragma unroll
          for (int zi = 0; zi < 4; ++zi){
            const int zz = (wv*4 + zi + dz + 15) & 15;
            bf16x8 bf = *(const bf16x8*)(x_lds + (zz*16 + ww)*64 + chunk);
#pragma unroll
            for (int mi = 0; mi < 4; ++mi)
              acc[zi][mi] = __builtin_amdgcn_mfma_f32_16x16x32_bf16(af[mi], bf, acc[zi][mi], 0, 0, 0);
          }
        }
      }
    }
  }

  // ---- epilogue: bias + fp32 store
  float bvals[4][4];
#pragma unroll
  for (int mi = 0; mi < 4; ++mi)
#pragma unroll
    for (int r = 0; r < 4; ++r)
      bvals[mi][r] = bias[mi*16 + q*4 + r];

  float* ob = out + (size_t)b*64*65536 + t*4096 + y*256 + wl;
#pragma unroll
  for (int zi = 0; zi < 4; ++zi){
    const int z = wv*4 + zi;
#pragma unroll
    for (int mi = 0; mi < 4; ++mi){
#pragma unroll
      for (int r = 0; r < 4; ++r){
        const int co = mi*16 + q*4 + r;   // C/D: row = quad*4 + reg
        ob[(size_t)co*65536 + z*16] = acc[zi][mi][r] + bvals[mi][r];
      }
    }
  }
}

// ===================== FALLBACK (round-2 proven path) =======================
__global__ void repack_w_kernel(const float* __restrict__ w, u16* __restrict__ wp){
  int idx = blockIdx.x * 256 + threadIdx.x;
  if (idx >= 81*64*64) return;
  int cw  = idx & 31;
  int t1  = idx >> 5;
  int co  = t1 & 63; t1 >>= 6;
  int kc  = t1 & 1;  t1 >>= 1;
  int tap = t1;
  int dw = tap % 3, dz = (tap/3) % 3, dy = (tap/9) % 3, dt = tap/27;
  int ci = kc*32 + cw;
  int in_idx = ((((dt*64 + co)*64 + ci)*3 + dy)*3 + dz)*3 + dw;
  wp[idx] = f2bf(w[in_idx]);
}

__global__ __launch_bounds__(256, 2) void conv4d_mfma_kernel(
    const float* __restrict__ x, const u16* __restrict__ wp,
    const float* __restrict__ bias, float* __restrict__ out)
{
  __shared__ __attribute__((aligned(16))) u16 x_lds[256*72];
  __shared__ __attribute__((aligned(16))) u16 a_lds[3*2*64*32];
  const int bx = blockIdx.x;
  const int y = bx & 15, t = (bx >> 4) & 15, b = bx >> 8;
  const int tid  = threadIdx.x;
  const int lane = tid & 63;
  const int wv   = tid >> 6;
  const int wl   = lane & 15;
  const int q    = lane >> 4;
  floatx4 acc[4][4];
#pragma unroll
  for (int zi = 0; zi < 4; ++zi)
#pragma unroll
    for (int mi = 0; mi < 4; ++mi)
      acc[zi][mi] = (floatx4)0.0f;
  const float* xb = x + (size_t)b * 64 * 65536;
  for (int dt = 0; dt < 3; ++dt){
    const int tt = (t + dt + 15) & 15;
    for (int dy = 0; dy < 3; ++dy){
      const int yy = (y + dy + 15) & 15;
      __syncthreads();
      {
        const float* src = xb + tt*4096 + yy*256 + tid;
#pragma unroll
        for (int oct = 0; oct < 8; ++oct){
          float v[8];
#pragma unroll
          for (int j = 0; j < 8; ++j)
            v[j] = src[(size_t)(oct*8 + j) * 65536];
          short8 vv;
#pragma unroll
          for (int j = 0; j < 8; ++j) vv[j] = (short)f2bf(v[j]);
          *(short8*)(x_lds + tid*72 + oct*8) = vv;
        }
      }
      for (int dz = 0; dz < 3; ++dz){
        const int tap0 = ((dt*3 + dy)*3 + dz)*3;
        __syncthreads();
        {
          const u16* asrc = wp + (size_t)tap0 * 4096;
#pragma unroll
          for (int i = 0; i < 6; ++i){
            int e = (i*256 + tid) * 8;
            *(short8*)(a_lds + e) = *(const short8*)(asrc + e);
          }
        }
        __syncthreads();
#pragma unroll
        for (int dw = 0; dw < 3; ++dw){
          const int ww = (wl + dw + 15) & 15;
#pragma unroll
          for (int kc = 0; kc < 2; ++kc){
            bf16x8 af[4];
#pragma unroll
            for (int mi = 0; mi < 4; ++mi)
              af[mi] = *(const bf16x8*)(a_lds + ((dw*2 + kc)*64 + mi*16 + wl)*32 + q*8);
#pragma unroll
            for (int zi = 0; zi < 4; ++zi){
              const int zz = (wv*4 + zi + dz + 15) & 15;
              bf16x8 bf = *(const bf16x8*)(x_lds + (zz*16 + ww)*72 + kc*32 + q*8);
#pragma unroll
              for (int mi = 0; mi < 4; ++mi)
                acc[zi][mi] = __builtin_amdgcn_mfma_f32_16x16x32_bf16(af[mi], bf, acc[zi][mi], 0, 0, 0);
            }
          }
        }
      }
    }
  }
  float bvals[4][4];
#pragma unroll
  for (int mi = 0; mi < 4; ++mi)
#pragma unroll
    for (int r = 0; r < 4; ++r)
      bvals[mi][r] = bias[mi*16 + q*4 + r];
  float* ob = out + (size_t)b * 64 * 65536 + t*4096 + y*256 + wl;
#pragma unroll
  for (int zi = 0; zi < 4; ++zi){
    const int z = wv*4 + zi;
#pragma unroll
    for (int mi = 0; mi < 4; ++mi){
#pragma unroll
      for (int r = 0; r < 4; ++r){
        const int co = mi*16 + q*4 + r;
        ob[(size_t)co*65536 + z*16] = acc[zi][mi][r] + bvals[mi][r];
      }
    }
  }
}

extern "C" void kernel_launch(void* const* d_in, const int* in_sizes, int n_in,
                              void* d_out, int out_size, void* d_ws, size_t ws_size,
                              hipStream_t stream) {
  const float* x    = (const float*)d_in[0];
  const float* w    = (const float*)d_in[1];
  const float* bias = (const float*)d_in[2];
  float* out = (float*)d_out;

  const size_t xp_bytes = (size_t)1024 * 16384 * 2;   // 33.55 MB bf16 transposed x
  const size_t wp_bytes = 81*64*64*2;                  // 663.5 KB packed weights
  if (ws_size >= xp_bytes + wp_bytes){
    u16* xp = (u16*)d_ws;
    u16* wp = (u16*)((char*)d_ws + xp_bytes);
    prep_kernel<<<1024 + 1296, 256, 0, stream>>>(x, w, xp, wp);
    conv4d_mfma_v5<<<1024, 256, 0, stream>>>(xp, wp, bias, out);
  } else {
    u16* wp = (u16*)d_ws;
    repack_w_kernel<<<1296, 256, 0, stream>>>(w, wp);
    conv4d_mfma_kernel<<<1024, 256, 0, stream>>>(x, wp, bias, out);
  }
}

// Round 4
// 282.227 us; speedup vs baseline: 1.7627x; 1.7627x over previous
//
#include <hip/hip_runtime.h>

typedef unsigned short u16;
typedef __attribute__((ext_vector_type(8))) __bf16 bf16x8;
typedef __attribute__((ext_vector_type(8))) short short8;
typedef __attribute__((ext_vector_type(4))) short short4v;
typedef __attribute__((ext_vector_type(4))) float floatx4;

__device__ __forceinline__ u16 f2bf(float f){
  unsigned int x = __float_as_uint(f);
  unsigned int r = (x + 0x7fffu + ((x >> 16) & 1u)) >> 16;  // RTNE
  return (u16)r;
}

// async 16B global->LDS copy; lds base must be wave-uniform (HW: base + lane*16)
#define GLL(g, l) __builtin_amdgcn_global_load_lds( \
    (const __attribute__((address_space(1))) void*)(g), \
    (__attribute__((address_space(3))) void*)(l), 16, 0, 0)

// ============================ PREP PASS =====================================
// blocks 0..1023: x[b][ci][t][y][zw] fp32 -> xp[b][t][y][zw][ci] bf16,
//   16B chunks XOR-placed: chunk position p holds ci-oct (p ^ (zw&7)).
//   LDS-staged transpose: float4 coalesced reads, coalesced b128 stores.
// blocks 1024..2319: weight fp32 -> wp[tap][kc][co][ci32] bf16 (coalesced reads).
__global__ void prep_kernel(const float* __restrict__ x, const float* __restrict__ w,
                            u16* __restrict__ xp, u16* __restrict__ wp){
  __shared__ __attribute__((aligned(16))) u16 I[16384];  // 32 KB: [ci][granule] swizzled
  const int bx = blockIdx.x;
  const int tid = threadIdx.x;
  if (bx < 1024){
    const int y = bx & 15, t = (bx >> 4) & 15, b = bx >> 8;
    const int l  = tid & 63;   // lane
    const int wv = tid >> 6;   // wave
    const float* xb = x + (size_t)b*64*65536 + t*4096 + y*256;

    // ---- Phase A: read + convert + swizzled LDS write ----
#pragma unroll
    for (int j = 0; j < 16; ++j){
      const int ci = j*4 + wv;
      const float4 f = *(const float4*)(xb + (size_t)ci*65536 + l*4);
      const int o  = ci >> 3;
      const int gp = l ^ o ^ ((o & 1) << 3);     // granule swizzle (bijective per ci)
      short4v hv;
      hv[0] = (short)f2bf(f.x);
      hv[1] = (short)f2bf(f.y);
      hv[2] = (short)f2bf(f.z);
      hv[3] = (short)f2bf(f.w);
      *(short4v*)(I + ci*256 + gp*4) = hv;       // b64, 8B aligned
    }
    __syncthreads();

    // ---- Phase B: gather + coalesced b128 global store ----
    const int p  = tid & 7;
    const int r0 = tid >> 3;
    u16* dst = xp + (size_t)bx*16384;
#pragma unroll
    for (int it = 0; it < 8; ++it){
      const int zw = it*32 + r0;
      const int o  = p ^ (zw & 7);
      const int g  = zw >> 2;
      const int gp = g ^ o ^ ((o & 1) << 3);
      const int base = gp*4 + (zw & 3);
      short8 vv;
#pragma unroll
      for (int m = 0; m < 8; ++m)
        vv[m] = (short)I[(o*8 + m)*256 + base];
      *(short8*)(dst + it*2048 + tid*8) = vv;    // 1 KB contiguous per wave-instr
    }
  } else {
    int idx = (bx - 1024)*256 + tid;   // linear over w input (coalesced)
    if (idx < 81*64*64){
      int r  = idx;
      int dw = r % 3; r /= 3;
      int dz = r % 3; r /= 3;
      int dy = r % 3; r /= 3;
      int ci = r & 63; r >>= 6;
      int co = r & 63; r >>= 6;
      int dt = r;
      int tap = ((dt*3 + dy)*3 + dz)*3 + dw;
      int kc = ci >> 5, ci32 = ci & 31;
      wp[tap*4096 + kc*2048 + co*32 + ci32] = f2bf(w[idx]);
    }
  }
}

// ============================ MAIN KERNEL ===================================
// v6 = v5's structure (A-fragments direct from global wp — L1/L2-resident,
// proven CORRECT in round 3) with the spill removed and the restage hidden:
//  - __launch_bounds__(256,2): 256-VGPR budget. v5's 426 µs was a spill
//    artifact of the 128-VGPR cap at (256,4) (VGPR_Count=64, 1.5 GB scratch).
//  - LDS = x plane only (32 KB). LDS-pipe (the v4 bottleneck, ~81% busy)
//    drops by half: B-reads only (24 b128/slab/wave vs 48).
//  - T14 async-stage split: next x-plane global->reg loads issued at the TOP
//    of each dtdy (~5600 cyc of MFMA ahead of use); boundary is
//    sync -> ds_write(regs) -> sync, no exposed L2 round trip.
//  - no per-slab barriers at all: 17 barriers/block (vs 34 in v4).
//  - T5 setprio around the MFMA cluster (waves free-run -> role diversity).
__global__ __launch_bounds__(256, 2) void conv4d_mfma_v6(
    const u16* __restrict__ xp, const u16* __restrict__ wp,
    const float* __restrict__ bias, float* __restrict__ out)
{
  __shared__ __attribute__((aligned(16))) u16 x_lds[16384];     // [zw][ci], XOR chunks

  // XCD-aware swizzle: XCD c = bx&7 owns (b = c>>1, y-half = c&1).
  const int bx = blockIdx.x;
  const int c = bx & 7, j = bx >> 3;
  const int b = c >> 1, t = j >> 3, y = (c & 1)*8 + (j & 7);

  const int tid  = threadIdx.x;
  const int lane = tid & 63;
  const int wv   = tid >> 6;
  const int wl   = lane & 15;   // B: n (w-pos); A: m (co row within 16-tile)
  const int q    = lane >> 4;   // k-octet selector; D: co = quad*4+reg

  floatx4 acc[4][4];
#pragma unroll
  for (int zi = 0; zi < 4; ++zi)
#pragma unroll
    for (int mi = 0; mi < 4; ++mi)
      acc[zi][mi] = (floatx4)0.0f;

  // per-thread A base: wp + co(wl)-row + ci-octet(q); tap/kc/mi folded below.
  const u16* wpt = wp + wl*32 + q*8;

  // prologue: GLL plane 0
  {
    const int tt = (t + 15) & 15, yy = (y + 15) & 15;
    const u16* plane = xp + (size_t)(((b*16 + tt)*16) + yy) * 16384;
#pragma unroll
    for (int i = 0; i < 8; ++i)
      GLL(plane + wv*4096 + i*512 + lane*8, x_lds + wv*4096 + i*512);
  }
  __syncthreads();

  for (int dtdy = 0; dtdy < 9; ++dtdy){
    // ---- T14: prefetch next plane into registers (latency hidden under
    //      this dtdy's 288 MFMAs) ----
    bf16x8 xr[8];
    if (dtdy < 8){
      const int dt2 = (dtdy + 1) / 3, dy2 = (dtdy + 1) % 3;
      const int tt = (t + dt2 + 15) & 15;
      const int yy = (y + dy2 + 15) & 15;
      const u16* nplane = xp + (size_t)(((b*16 + tt)*16) + yy) * 16384;
#pragma unroll
      for (int i = 0; i < 8; ++i)
        xr[i] = *(const bf16x8*)(nplane + wv*4096 + i*512 + lane*8);
    }

    // ---- compute 3 slabs (no barriers inside) ----
#pragma unroll
    for (int dz = 0; dz < 3; ++dz){
      const u16* ab = wpt + (size_t)((dtdy*3 + dz) * 3) * 4096;   // 3-tap slab base
#pragma unroll
      for (int dw = 0; dw < 3; ++dw){
        const int ww = (wl + dw + 15) & 15;
        const int wx = ww & 7;
#pragma unroll
        for (int kc = 0; kc < 2; ++kc){
          bf16x8 af[4];
#pragma unroll
          for (int mi = 0; mi < 4; ++mi)
            af[mi] = *(const bf16x8*)(ab + dw*4096 + kc*2048 + mi*512);  // global, L1/L2-hot
          const int chunk = ((kc*4 + q) ^ wx)*8;
          __builtin_amdgcn_s_setprio(1);
#pragma unroll
          for (int zi = 0; zi < 4; ++zi){
            const int zz = (wv*4 + zi + dz + 15) & 15;
            bf16x8 bf = *(const bf16x8*)(x_lds + (zz*16 + ww)*64 + chunk);
#pragma unroll
            for (int mi = 0; mi < 4; ++mi)
              acc[zi][mi] = __builtin_amdgcn_mfma_f32_16x16x32_bf16(af[mi], bf, acc[zi][mi], 0, 0, 0);
          }
          __builtin_amdgcn_s_setprio(0);
        }
      }
    }

    // ---- boundary: swap in the prefetched plane ----
    if (dtdy < 8){
      __syncthreads();                      // all waves done reading x_lds
#pragma unroll
      for (int i = 0; i < 8; ++i)
        *(bf16x8*)(x_lds + wv*4096 + i*512 + lane*8) = xr[i];  // data already in regs
      __syncthreads();                      // plane visible
    }
  }

  // ---- epilogue: bias + fp32 store
  float bvals[4][4];
#pragma unroll
  for (int mi = 0; mi < 4; ++mi)
#pragma unroll
    for (int r = 0; r < 4; ++r)
      bvals[mi][r] = bias[mi*16 + q*4 + r];

  float* ob = out + (size_t)b*64*65536 + t*4096 + y*256 + wl;
#pragma unroll
  for (int zi = 0; zi < 4; ++zi){
    const int z = wv*4 + zi;
#pragma unroll
    for (int mi = 0; mi < 4; ++mi){
#pragma unroll
      for (int r = 0; r < 4; ++r){
        const int co = mi*16 + q*4 + r;   // C/D: row = quad*4 + reg
        ob[(size_t)co*65536 + z*16] = acc[zi][mi][r] + bvals[mi][r];
      }
    }
  }
}

// ===================== FALLBACK (round-2 proven path) =======================
__global__ void repack_w_kernel(const float* __restrict__ w, u16* __restrict__ wp){
  int idx = blockIdx.x * 256 + threadIdx.x;
  if (idx >= 81*64*64) return;
  int cw  = idx & 31;
  int t1  = idx >> 5;
  int co  = t1 & 63; t1 >>= 6;
  int kc  = t1 & 1;  t1 >>= 1;
  int tap = t1;
  int dw = tap % 3, dz = (tap/3) % 3, dy = (tap/9) % 3, dt = tap/27;
  int ci = kc*32 + cw;
  int in_idx = ((((dt*64 + co)*64 + ci)*3 + dy)*3 + dz)*3 + dw;
  wp[idx] = f2bf(w[in_idx]);
}

__global__ __launch_bounds__(256, 2) void conv4d_mfma_kernel(
    const float* __restrict__ x, const u16* __restrict__ wp,
    const float* __restrict__ bias, float* __restrict__ out)
{
  __shared__ __attribute__((aligned(16))) u16 x_lds[256*72];
  __shared__ __attribute__((aligned(16))) u16 a_lds[3*2*64*32];
  const int bx = blockIdx.x;
  const int y = bx & 15, t = (bx >> 4) & 15, b = bx >> 8;
  const int tid  = threadIdx.x;
  const int lane = tid & 63;
  const int wv   = tid >> 6;
  const int wl   = lane & 15;
  const int q    = lane >> 4;
  floatx4 acc[4][4];
#pragma unroll
  for (int zi = 0; zi < 4; ++zi)
#pragma unroll
    for (int mi = 0; mi < 4; ++mi)
      acc[zi][mi] = (floatx4)0.0f;
  const float* xb = x + (size_t)b * 64 * 65536;
  for (int dt = 0; dt < 3; ++dt){
    const int tt = (t + dt + 15) & 15;
    for (int dy = 0; dy < 3; ++dy){
      const int yy = (y + dy + 15) & 15;
      __syncthreads();
      {
        const float* src = xb + tt*4096 + yy*256 + tid;
#pragma unroll
        for (int oct = 0; oct < 8; ++oct){
          float v[8];
#pragma unroll
          for (int j = 0; j < 8; ++j)
            v[j] = src[(size_t)(oct*8 + j) * 65536];
          short8 vv;
#pragma unroll
          for (int j = 0; j < 8; ++j) vv[j] = (short)f2bf(v[j]);
          *(short8*)(x_lds + tid*72 + oct*8) = vv;
        }
      }
      for (int dz = 0; dz < 3; ++dz){
        const int tap0 = ((dt*3 + dy)*3 + dz)*3;
        __syncthreads();
        {
          const u16* asrc = wp + (size_t)tap0 * 4096;
#pragma unroll
          for (int i = 0; i < 6; ++i){
            int e = (i*256 + tid) * 8;
            *(short8*)(a_lds + e) = *(const short8*)(asrc + e);
          }
        }
        __syncthreads();
#pragma unroll
        for (int dw = 0; dw < 3; ++dw){
          const int ww = (wl + dw + 15) & 15;
#pragma unroll
          for (int kc = 0; kc < 2; ++kc){
            bf16x8 af[4];
#pragma unroll
            for (int mi = 0; mi < 4; ++mi)
              af[mi] = *(const bf16x8*)(a_lds + ((dw*2 + kc)*64 + mi*16 + wl)*32 + q*8);
#pragma unroll
            for (int zi = 0; zi < 4; ++zi){
              const int zz = (wv*4 + zi + dz + 15) & 15;
              bf16x8 bf = *(const bf16x8*)(x_lds + (zz*16 + ww)*72 + kc*32 + q*8);
#pragma unroll
              for (int mi = 0; mi < 4; ++mi)
                acc[zi][mi] = __builtin_amdgcn_mfma_f32_16x16x32_bf16(af[mi], bf, acc[zi][mi], 0, 0, 0);
            }
          }
        }
      }
    }
  }
  float bvals[4][4];
#pragma unroll
  for (int mi = 0; mi < 4; ++mi)
#pragma unroll
    for (int r = 0; r < 4; ++r)
      bvals[mi][r] = bias[mi*16 + q*4 + r];
  float* ob = out + (size_t)b * 64 * 65536 + t*4096 + y*256 + wl;
#pragma unroll
  for (int zi = 0; zi < 4; ++zi){
    const int z = wv*4 + zi;
#pragma unroll
    for (int mi = 0; mi < 4; ++mi){
#pragma unroll
      for (int r = 0; r < 4; ++r){
        const int co = mi*16 + q*4 + r;
        ob[(size_t)co*65536 + z*16] = acc[zi][mi][r] + bvals[mi][r];
      }
    }
  }
}

extern "C" void kernel_launch(void* const* d_in, const int* in_sizes, int n_in,
                              void* d_out, int out_size, void* d_ws, size_t ws_size,
                              hipStream_t stream) {
  const float* x    = (const float*)d_in[0];
  const float* w    = (const float*)d_in[1];
  const float* bias = (const float*)d_in[2];
  float* out = (float*)d_out;

  const size_t xp_bytes = (size_t)1024 * 16384 * 2;   // 33.55 MB bf16 transposed x
  const size_t wp_bytes = 81*64*64*2;                  // 663.5 KB packed weights
  if (ws_size >= xp_bytes + wp_bytes){
    u16* xp = (u16*)d_ws;
    u16* wp = (u16*)((char*)d_ws + xp_bytes);
    prep_kernel<<<1024 + 1296, 256, 0, stream>>>(x, w, xp, wp);
    conv4d_mfma_v6<<<1024, 256, 0, stream>>>(xp, wp, bias, out);
  } else {
    u16* wp = (u16*)d_ws;
    repack_w_kernel<<<1296, 256, 0, stream>>>(w, wp);
    conv4d_mfma_kernel<<<1024, 256, 0, stream>>>(x, wp, bias, out);
  }
}

// Round 5
// 277.149 us; speedup vs baseline: 1.7950x; 1.0183x over previous
//
#include <hip/hip_runtime.h>

typedef unsigned short u16;
typedef __attribute__((ext_vector_type(8))) __bf16 bf16x8;
typedef __attribute__((ext_vector_type(8))) short short8;
typedef __attribute__((ext_vector_type(4))) short short4v;
typedef __attribute__((ext_vector_type(4))) float floatx4;

__device__ __forceinline__ u16 f2bf(float f){
  unsigned int x = __float_as_uint(f);
  unsigned int r = (x + 0x7fffu + ((x >> 16) & 1u)) >> 16;  // RTNE
  return (u16)r;
}

// async 16B global->LDS copy; lds base must be wave-uniform (HW: base + lane*16)
#define GLL(g, l) __builtin_amdgcn_global_load_lds( \
    (const __attribute__((address_space(1))) void*)(g), \
    (__attribute__((address_space(3))) void*)(l), 16, 0, 0)

// ============================ PREP PASS =====================================
// blocks 0..1023: x[b][ci][t][y][zw] fp32 -> xp[b][t][y][zw][ci] bf16,
//   16B chunks XOR-placed: chunk position p holds ci-oct (p ^ (zw&7)).
//   LDS-staged transpose: float4 coalesced reads, coalesced b128 stores.
// blocks 1024..2319: weight fp32 -> wp[tap][kc][co][ci32] bf16 (coalesced reads).
__global__ void prep_kernel(const float* __restrict__ x, const float* __restrict__ w,
                            u16* __restrict__ xp, u16* __restrict__ wp){
  __shared__ __attribute__((aligned(16))) u16 I[16384];  // 32 KB: [ci][granule] swizzled
  const int bx = blockIdx.x;
  const int tid = threadIdx.x;
  if (bx < 1024){
    const int y = bx & 15, t = (bx >> 4) & 15, b = bx >> 8;
    const int l  = tid & 63;   // lane
    const int wv = tid >> 6;   // wave
    const float* xb = x + (size_t)b*64*65536 + t*4096 + y*256;

    // ---- Phase A: read + convert + swizzled LDS write ----
#pragma unroll
    for (int j = 0; j < 16; ++j){
      const int ci = j*4 + wv;
      const float4 f = *(const float4*)(xb + (size_t)ci*65536 + l*4);
      const int o  = ci >> 3;
      const int gp = l ^ o ^ ((o & 1) << 3);     // granule swizzle (bijective per ci)
      short4v hv;
      hv[0] = (short)f2bf(f.x);
      hv[1] = (short)f2bf(f.y);
      hv[2] = (short)f2bf(f.z);
      hv[3] = (short)f2bf(f.w);
      *(short4v*)(I + ci*256 + gp*4) = hv;       // b64, 8B aligned
    }
    __syncthreads();

    // ---- Phase B: gather + coalesced b128 global store ----
    const int p  = tid & 7;
    const int r0 = tid >> 3;
    u16* dst = xp + (size_t)bx*16384;
#pragma unroll
    for (int it = 0; it < 8; ++it){
      const int zw = it*32 + r0;
      const int o  = p ^ (zw & 7);
      const int g  = zw >> 2;
      const int gp = g ^ o ^ ((o & 1) << 3);
      const int base = gp*4 + (zw & 3);
      short8 vv;
#pragma unroll
      for (int m = 0; m < 8; ++m)
        vv[m] = (short)I[(o*8 + m)*256 + base];
      *(short8*)(dst + it*2048 + tid*8) = vv;    // 1 KB contiguous per wave-instr
    }
  } else {
    int idx = (bx - 1024)*256 + tid;   // linear over w input (coalesced)
    if (idx < 81*64*64){
      int r  = idx;
      int dw = r % 3; r /= 3;
      int dz = r % 3; r /= 3;
      int dy = r % 3; r /= 3;
      int ci = r & 63; r >>= 6;
      int co = r & 63; r >>= 6;
      int dt = r;
      int tap = ((dt*3 + dy)*3 + dz)*3 + dw;
      int kc = ci >> 5, ci32 = ci & 31;
      wp[tap*4096 + kc*2048 + co*32 + ci32] = f2bf(w[idx]);
    }
  }
}

// ============================ MAIN KERNEL ===================================
// v7 = v6's structure + explicit 3-deep REGISTER pipeline for A-fragments.
// Round-4 evidence: v6's regression (200 vs 150 µs, MfmaUtil 38) was the
// serially-exposed L2 latency of per-group A loads (88 VGPR -> compiler
// couldn't pipeline). Here group G+2's A-set is loaded while G computes:
// consume-wait is a counted vmcnt(8), never a drain (T4 at group granularity).
// 18 groups/plane % 3 == 0 -> rotating buffer index u%3 is COMPILE-TIME
// (no dynamic indexing -> no scratch; rule #20).
// ds-pipe carries only B-reads (24 b128/slab/wave, measured conflict-free);
// barriers 17/block; LDS 32 KB; ~150 VGPR -> 3 waves/SIMD.
__global__ __launch_bounds__(256, 2) void conv4d_mfma_v7(
    const u16* __restrict__ xp, const u16* __restrict__ wp,
    const float* __restrict__ bias, float* __restrict__ out)
{
  __shared__ __attribute__((aligned(16))) u16 x_lds[16384];     // [zw][ci], XOR chunks

  // XCD-aware swizzle: XCD c = bx&7 owns (b = c>>1, y-half = c&1).
  const int bx = blockIdx.x;
  const int c = bx & 7, j = bx >> 3;
  const int b = c >> 1, t = j >> 3, y = (c & 1)*8 + (j & 7);

  const int tid  = threadIdx.x;
  const int lane = tid & 63;
  const int wv   = tid >> 6;
  const int wl   = lane & 15;   // B: n (w-pos); A: m (co row within 16-tile)
  const int q    = lane >> 4;   // k-octet selector; D: co = quad*4+reg

  floatx4 acc[4][4];
#pragma unroll
  for (int zi = 0; zi < 4; ++zi)
#pragma unroll
    for (int mi = 0; mi < 4; ++mi)
      acc[zi][mi] = (floatx4)0.0f;

  // per-thread A base; group G's fragment mi lives at wpt + G*2048 + mi*512
  // (G = tap*2 + kc; wp layout [tap][kc][co][ci32]).
  const u16* wpt = wp + wl*32 + q*8;

  bf16x8 afb[3][4];                       // 3-deep group pipeline (48 VGPR)
  auto ldaf = [&](int G, bf16x8 (&dst)[4]){
    const u16* ab = wpt + G*2048;
#pragma unroll
    for (int mi = 0; mi < 4; ++mi)
      dst[mi] = *(const bf16x8*)(ab + mi*512);   // global, L1/L2-hot, coalesced 1 KB
  };

  auto stage_x = [&](int dtdy){
    const int dt = dtdy / 3, dy = dtdy % 3;
    const int tt = (t + dt + 15) & 15;
    const int yy = (y + dy + 15) & 15;
    const u16* plane = xp + (size_t)(((b*16 + tt)*16) + yy) * 16384;
#pragma unroll
    for (int i = 0; i < 8; ++i)
      GLL(plane + wv*4096 + i*512 + lane*8, x_lds + wv*4096 + i*512);
  };

  // prologue: A-pipeline warm-up + x plane 0
  ldaf(0, afb[0]);
  ldaf(1, afb[1]);
  stage_x(0);
  __syncthreads();                        // drains GLL + warm-up loads

  for (int dtdy = 0; dtdy < 9; ++dtdy){
    if (dtdy){
      __syncthreads();                    // all waves done reading previous plane
      stage_x(dtdy);
      __syncthreads();                    // plane ready (also drains af prefetches)
    }

    const int Gbase = dtdy*18;
#pragma unroll
    for (int u = 0; u < 18; ++u){
      // ---- prefetch group G+2 (consumed 2 bodies later) ----
      int Gn = Gbase + u + 2;
      if (Gn > 161) Gn = 161;             // tail: dead loads, never consumed
      ldaf(Gn, afb[(u + 2) % 3]);         // (u+2)%3 is compile-time

      // ---- compute group u: dz,dw,kc compile-time ----
      const int dz = u / 6, dw = (u >> 1) % 3, kc = u & 1;
      const int ww = (wl + dw + 15) & 15;
      const int wx = ww & 7;
      const int chunk = ((kc*4 + q) ^ wx)*8;
      bf16x8 (&af)[4] = afb[u % 3];
      __builtin_amdgcn_s_setprio(1);
#pragma unroll
      for (int zi = 0; zi < 4; ++zi){
        const int zz = (wv*4 + zi + dz + 15) & 15;
        bf16x8 bfv = *(const bf16x8*)(x_lds + (zz*16 + ww)*64 + chunk);
#pragma unroll
        for (int mi = 0; mi < 4; ++mi)
          acc[zi][mi] = __builtin_amdgcn_mfma_f32_16x16x32_bf16(af[mi], bfv, acc[zi][mi], 0, 0, 0);
      }
      __builtin_amdgcn_s_setprio(0);
    }
  }

  // ---- epilogue: bias + fp32 store
  float bvals[4][4];
#pragma unroll
  for (int mi = 0; mi < 4; ++mi)
#pragma unroll
    for (int r = 0; r < 4; ++r)
      bvals[mi][r] = bias[mi*16 + q*4 + r];

  float* ob = out + (size_t)b*64*65536 + t*4096 + y*256 + wl;
#pragma unroll
  for (int zi = 0; zi < 4; ++zi){
    const int z = wv*4 + zi;
#pragma unroll
    for (int mi = 0; mi < 4; ++mi){
#pragma unroll
      for (int r = 0; r < 4; ++r){
        const int co = mi*16 + q*4 + r;   // C/D: row = quad*4 + reg
        ob[(size_t)co*65536 + z*16] = acc[zi][mi][r] + bvals[mi][r];
      }
    }
  }
}

// ===================== FALLBACK (round-2 proven path) =======================
__global__ void repack_w_kernel(const float* __restrict__ w, u16* __restrict__ wp){
  int idx = blockIdx.x * 256 + threadIdx.x;
  if (idx >= 81*64*64) return;
  int cw  = idx & 31;
  int t1  = idx >> 5;
  int co  = t1 & 63; t1 >>= 6;
  int kc  = t1 & 1;  t1 >>= 1;
  int tap = t1;
  int dw = tap % 3, dz = (tap/3) % 3, dy = (tap/9) % 3, dt = tap/27;
  int ci = kc*32 + cw;
  int in_idx = ((((dt*64 + co)*64 + ci)*3 + dy)*3 + dz)*3 + dw;
  wp[idx] = f2bf(w[in_idx]);
}

__global__ __launch_bounds__(256, 2) void conv4d_mfma_kernel(
    const float* __restrict__ x, const u16* __restrict__ wp,
    const float* __restrict__ bias, float* __restrict__ out)
{
  __shared__ __attribute__((aligned(16))) u16 x_lds[256*72];
  __shared__ __attribute__((aligned(16))) u16 a_lds[3*2*64*32];
  const int bx = blockIdx.x;
  const int y = bx & 15, t = (bx >> 4) & 15, b = bx >> 8;
  const int tid  = threadIdx.x;
  const int lane = tid & 63;
  const int wv   = tid >> 6;
  const int wl   = lane & 15;
  const int q    = lane >> 4;
  floatx4 acc[4][4];
#pragma unroll
  for (int zi = 0; zi < 4; ++zi)
#pragma unroll
    for (int mi = 0; mi < 4; ++mi)
      acc[zi][mi] = (floatx4)0.0f;
  const float* xb = x + (size_t)b * 64 * 65536;
  for (int dt = 0; dt < 3; ++dt){
    const int tt = (t + dt + 15) & 15;
    for (int dy = 0; dy < 3; ++dy){
      const int yy = (y + dy + 15) & 15;
      __syncthreads();
      {
        const float* src = xb + tt*4096 + yy*256 + tid;
#pragma unroll
        for (int oct = 0; oct < 8; ++oct){
          float v[8];
#pragma unroll
          for (int j = 0; j < 8; ++j)
            v[j] = src[(size_t)(oct*8 + j) * 65536];
          short8 vv;
#pragma unroll
          for (int j = 0; j < 8; ++j) vv[j] = (short)f2bf(v[j]);
          *(short8*)(x_lds + tid*72 + oct*8) = vv;
        }
      }
      for (int dz = 0; dz < 3; ++dz){
        const int tap0 = ((dt*3 + dy)*3 + dz)*3;
        __syncthreads();
        {
          const u16* asrc = wp + (size_t)tap0 * 4096;
#pragma unroll
          for (int i = 0; i < 6; ++i){
            int e = (i*256 + tid) * 8;
            *(short8*)(a_lds + e) = *(const short8*)(asrc + e);
          }
        }
        __syncthreads();
#pragma unroll
        for (int dw = 0; dw < 3; ++dw){
          const int ww = (wl + dw + 15) & 15;
#pragma unroll
          for (int kc = 0; kc < 2; ++kc){
            bf16x8 af[4];
#pragma unroll
            for (int mi = 0; mi < 4; ++mi)
              af[mi] = *(const bf16x8*)(a_lds + ((dw*2 + kc)*64 + mi*16 + wl)*32 + q*8);
#pragma unroll
            for (int zi = 0; zi < 4; ++zi){
              const int zz = (wv*4 + zi + dz + 15) & 15;
              bf16x8 bf = *(const bf16x8*)(x_lds + (zz*16 + ww)*72 + kc*32 + q*8);
#pragma unroll
              for (int mi = 0; mi < 4; ++mi)
                acc[zi][mi] = __builtin_amdgcn_mfma_f32_16x16x32_bf16(af[mi], bf, acc[zi][mi], 0, 0, 0);
            }
          }
        }
      }
    }
  }
  float bvals[4][4];
#pragma unroll
  for (int mi = 0; mi < 4; ++mi)
#pragma unroll
    for (int r = 0; r < 4; ++r)
      bvals[mi][r] = bias[mi*16 + q*4 + r];
  float* ob = out + (size_t)b * 64 * 65536 + t*4096 + y*256 + wl;
#pragma unroll
  for (int zi = 0; zi < 4; ++zi){
    const int z = wv*4 + zi;
#pragma unroll
    for (int mi = 0; mi < 4; ++mi){
#pragma unroll
      for (int r = 0; r < 4; ++r){
        const int co = mi*16 + q*4 + r;
        ob[(size_t)co*65536 + z*16] = acc[zi][mi][r] + bvals[mi][r];
      }
    }
  }
}

extern "C" void kernel_launch(void* const* d_in, const int* in_sizes, int n_in,
                              void* d_out, int out_size, void* d_ws, size_t ws_size,
                              hipStream_t stream) {
  const float* x    = (const float*)d_in[0];
  const float* w    = (const float*)d_in[1];
  const float* bias = (const float*)d_in[2];
  float* out = (float*)d_out;

  const size_t xp_bytes = (size_t)1024 * 16384 * 2;   // 33.55 MB bf16 transposed x
  const size_t wp_bytes = 81*64*64*2;                  // 663.5 KB packed weights
  if (ws_size >= xp_bytes + wp_bytes){
    u16* xp = (u16*)d_ws;
    u16* wp = (u16*)((char*)d_ws + xp_bytes);
    prep_kernel<<<1024 + 1296, 256, 0, stream>>>(x, w, xp, wp);
    conv4d_mfma_v7<<<1024, 256, 0, stream>>>(xp, wp, bias, out);
  } else {
    u16* wp = (u16*)d_ws;
    repack_w_kernel<<<1296, 256, 0, stream>>>(w, wp);
    conv4d_mfma_kernel<<<1024, 256, 0, stream>>>(x, wp, bias, out);
  }
}

// Round 6
// 230.428 us; speedup vs baseline: 2.1590x; 1.2028x over previous
//
#include <hip/hip_runtime.h>

typedef unsigned short u16;
typedef __attribute__((ext_vector_type(8))) __bf16 bf16x8;
typedef __attribute__((ext_vector_type(8))) short short8;
typedef __attribute__((ext_vector_type(4))) short short4v;
typedef __attribute__((ext_vector_type(4))) float floatx4;

__device__ __forceinline__ u16 f2bf(float f){
  unsigned int x = __float_as_uint(f);
  unsigned int r = (x + 0x7fffu + ((x >> 16) & 1u)) >> 16;  // RTNE
  return (u16)r;
}

// async 16B global->LDS copy; lds base must be wave-uniform (HW: base + lane*16)
#define GLL(g, l) __builtin_amdgcn_global_load_lds( \
    (const __attribute__((address_space(1))) void*)(g), \
    (__attribute__((address_space(3))) void*)(l), 16, 0, 0)

// ============================ PREP PASS =====================================
// blocks 0..1023: x[b][ci][t][y][zw] fp32 -> xp[b][t][y][zw][ci] bf16,
//   16B chunks XOR-placed: chunk position p holds ci-oct (p ^ (zw&7)).
//   LDS-staged transpose: float4 coalesced reads, coalesced b128 stores.
// blocks 1024..2319: weight fp32 -> wp[tap][kc][co][ci32] bf16 (coalesced reads).
__global__ void prep_kernel(const float* __restrict__ x, const float* __restrict__ w,
                            u16* __restrict__ xp, u16* __restrict__ wp){
  __shared__ __attribute__((aligned(16))) u16 I[16384];  // 32 KB: [ci][granule] swizzled
  const int bx = blockIdx.x;
  const int tid = threadIdx.x;
  if (bx < 1024){
    const int y = bx & 15, t = (bx >> 4) & 15, b = bx >> 8;
    const int l  = tid & 63;   // lane
    const int wv = tid >> 6;   // wave
    const float* xb = x + (size_t)b*64*65536 + t*4096 + y*256;

    // ---- Phase A: read + convert + swizzled LDS write ----
#pragma unroll
    for (int j = 0; j < 16; ++j){
      const int ci = j*4 + wv;
      const float4 f = *(const float4*)(xb + (size_t)ci*65536 + l*4);
      const int o  = ci >> 3;
      const int gp = l ^ o ^ ((o & 1) << 3);     // granule swizzle (bijective per ci)
      short4v hv;
      hv[0] = (short)f2bf(f.x);
      hv[1] = (short)f2bf(f.y);
      hv[2] = (short)f2bf(f.z);
      hv[3] = (short)f2bf(f.w);
      *(short4v*)(I + ci*256 + gp*4) = hv;       // b64, 8B aligned
    }
    __syncthreads();

    // ---- Phase B: gather + coalesced b128 global store ----
    const int p  = tid & 7;
    const int r0 = tid >> 3;
    u16* dst = xp + (size_t)bx*16384;
#pragma unroll
    for (int it = 0; it < 8; ++it){
      const int zw = it*32 + r0;
      const int o  = p ^ (zw & 7);
      const int g  = zw >> 2;
      const int gp = g ^ o ^ ((o & 1) << 3);
      const int base = gp*4 + (zw & 3);
      short8 vv;
#pragma unroll
      for (int m = 0; m < 8; ++m)
        vv[m] = (short)I[(o*8 + m)*256 + base];
      *(short8*)(dst + it*2048 + tid*8) = vv;    // 1 KB contiguous per wave-instr
    }
  } else {
    int idx = (bx - 1024)*256 + tid;   // linear over w input (coalesced)
    if (idx < 81*64*64){
      int r  = idx;
      int dw = r % 3; r /= 3;
      int dz = r % 3; r /= 3;
      int dy = r % 3; r /= 3;
      int ci = r & 63; r >>= 6;
      int co = r & 63; r >>= 6;
      int dt = r;
      int tap = ((dt*3 + dy)*3 + dz)*3 + dw;
      int kc = ci >> 5, ci32 = ci & 31;
      wp[tap*4096 + kc*2048 + co*32 + ci32] = f2bf(w[idx]);
    }
  }
}

// ============================ MAIN KERNEL ===================================
// v8 = v4's proven structure (A staged in LDS via GLL, double-buffered,
// 150 µs / MfmaUtil 52) + dz-REUSE restructure of the inner loop.
// Round-5 lesson: A-from-global is stuck ~190-200 µs (compiler sinks the
// prefetch: v7 VGPR=92 proves the 3-deep pipeline was collapsed). v4's
// binding pipe is LDS-read (48 b128/slab/wave -> ~104 µs vs MFMA 84 µs).
// Fix: the B-fragment row zz = wv*4+zi+dz-1 depends only on jj=zi+dz in
// [0,5] -> 6 unique rows per (dw,kc), v4 read 12. Stage A slabs along dw
// (3 taps = dz x {dtdy,dw}, same 24 KB, same GLL volume, same barriers),
// then per (dw,kc): 12 af + 6 bfr reads feed 48 MFMAs (0.375 reads/MFMA
// vs v4's 0.5). ds_reads/dtdy: 144 -> 108 => LDS pipe ~78 µs < MFMA 84 µs.
__global__ __launch_bounds__(256, 2) void conv4d_mfma_v8(
    const u16* __restrict__ xp, const u16* __restrict__ wp,
    const float* __restrict__ bias, float* __restrict__ out)
{
  __shared__ __attribute__((aligned(16))) u16 x_lds[16384];     // [zw][ci], XOR chunks
  __shared__ __attribute__((aligned(16))) u16 a_lds[2][12288];  // [dz][kc][co][ci32] x2

  // XCD-aware swizzle: XCD c = bx&7 owns (b = c>>1, y-half = c&1).
  const int bx = blockIdx.x;
  const int c = bx & 7, j = bx >> 3;
  const int b = c >> 1, t = j >> 3, y = (c & 1)*8 + (j & 7);

  const int tid  = threadIdx.x;
  const int lane = tid & 63;
  const int wv   = tid >> 6;
  const int wl   = lane & 15;   // B: n (w-pos); A: m (co row within 16-tile)
  const int q    = lane >> 4;   // k-octet selector; D: co = quad*4+reg

  floatx4 acc[4][4];
#pragma unroll
  for (int zi = 0; zi < 4; ++zi)
#pragma unroll
    for (int mi = 0; mi < 4; ++mi)
      acc[zi][mi] = (floatx4)0.0f;

  auto stage_x = [&](int dtdy){
    const int dt = dtdy / 3, dy = dtdy % 3;
    const int tt = (t + dt + 15) & 15;
    const int yy = (y + dy + 15) & 15;
    const u16* plane = xp + (size_t)(((b*16 + tt)*16) + yy) * 16384;
#pragma unroll
    for (int i = 0; i < 8; ++i)
      GLL(plane + wv*4096 + i*512 + lane*8, x_lds + wv*4096 + i*512);
  };
  // stage the dw-slab of (dtdy): taps {dtdy*9 + dz*3 + dw : dz=0,1,2},
  // three 8 KB regions at 12288-u16 stride -> a_lds[buf][dz*4096 ...]
  auto stage_a = [&](int dtdy, int dw, int buf){
    const u16* base = wp + (size_t)(dtdy*9 + dw) * 4096;
#pragma unroll
    for (int r = 0; r < 3; ++r)
#pragma unroll
      for (int i = 0; i < 2; ++i)
        GLL(base + (size_t)r*12288 + wv*1024 + i*512 + lane*8,
            a_lds[buf] + r*4096 + wv*1024 + i*512);
  };

  // prologue
  stage_x(0);
  stage_a(0, 0, 0);
  __syncthreads();   // drain: x plane 0 + first dw-slab ready

  for (int dtdy = 0; dtdy < 9; ++dtdy){
#pragma unroll
    for (int dw = 0; dw < 3; ++dw){
      const int cur = (dtdy + dw) & 1;          // slab index (dtdy*3+dw) parity
      const bool boundary = (dw == 2);
      if (!boundary)
        stage_a(dtdy, dw + 1, cur ^ 1);          // async prefetch next dw-slab

      // ---- compute dw-slab: 2 kc x (12 af + 6 bfr reads -> 48 MFMAs) ----
      const int ww = (wl + dw + 15) & 15;
      const int wx = ww & 7;
      const u16* abase = a_lds[cur] + wl*32 + q*8;
#pragma unroll
      for (int kc = 0; kc < 2; ++kc){
        const int chunk = ((kc*4 + q) ^ wx)*8;
        bf16x8 bfr[6];                           // 6 unique zz rows (jj = zi+dz)
#pragma unroll
        for (int jj = 0; jj < 6; ++jj){
          const int zz = (wv*4 + jj + 15) & 15;
          bfr[jj] = *(const bf16x8*)(x_lds + (zz*16 + ww)*64 + chunk);
        }
        bf16x8 af[3][4];
#pragma unroll
        for (int dz = 0; dz < 3; ++dz)
#pragma unroll
          for (int mi = 0; mi < 4; ++mi)
            af[dz][mi] = *(const bf16x8*)(abase + dz*4096 + kc*2048 + mi*512);
#pragma unroll
        for (int dz = 0; dz < 3; ++dz)
#pragma unroll
          for (int zi = 0; zi < 4; ++zi)
#pragma unroll
            for (int mi = 0; mi < 4; ++mi)
              acc[zi][mi] = __builtin_amdgcn_mfma_f32_16x16x32_bf16(
                  af[dz][mi], bfr[zi + dz], acc[zi][mi], 0, 0, 0);
      }

      if (boundary){
        if (dtdy < 8){
          __syncthreads();                      // compute done: x_lds + a bufs free
          stage_x(dtdy + 1);
          stage_a(dtdy + 1, 0, cur ^ 1);
          __syncthreads();                      // drain x + a for next dtdy
        }
      } else {
        __syncthreads();                        // next dw-slab visible
      }
    }
  }

  // ---- epilogue: bias + fp32 store
  float bvals[4][4];
#pragma unroll
  for (int mi = 0; mi < 4; ++mi)
#pragma unroll
    for (int r = 0; r < 4; ++r)
      bvals[mi][r] = bias[mi*16 + q*4 + r];

  float* ob = out + (size_t)b*64*65536 + t*4096 + y*256 + wl;
#pragma unroll
  for (int zi = 0; zi < 4; ++zi){
    const int z = wv*4 + zi;
#pragma unroll
    for (int mi = 0; mi < 4; ++mi){
#pragma unroll
      for (int r = 0; r < 4; ++r){
        const int co = mi*16 + q*4 + r;   // C/D: row = quad*4 + reg
        ob[(size_t)co*65536 + z*16] = acc[zi][mi][r] + bvals[mi][r];
      }
    }
  }
}

// ===================== FALLBACK (round-2 proven path) =======================
__global__ void repack_w_kernel(const float* __restrict__ w, u16* __restrict__ wp){
  int idx = blockIdx.x * 256 + threadIdx.x;
  if (idx >= 81*64*64) return;
  int cw  = idx & 31;
  int t1  = idx >> 5;
  int co  = t1 & 63; t1 >>= 6;
  int kc  = t1 & 1;  t1 >>= 1;
  int tap = t1;
  int dw = tap % 3, dz = (tap/3) % 3, dy = (tap/9) % 3, dt = tap/27;
  int ci = kc*32 + cw;
  int in_idx = ((((dt*64 + co)*64 + ci)*3 + dy)*3 + dz)*3 + dw;
  wp[idx] = f2bf(w[in_idx]);
}

__global__ __launch_bounds__(256, 2) void conv4d_mfma_kernel(
    const float* __restrict__ x, const u16* __restrict__ wp,
    const float* __restrict__ bias, float* __restrict__ out)
{
  __shared__ __attribute__((aligned(16))) u16 x_lds[256*72];
  __shared__ __attribute__((aligned(16))) u16 a_lds[3*2*64*32];
  const int bx = blockIdx.x;
  const int y = bx & 15, t = (bx >> 4) & 15, b = bx >> 8;
  const int tid  = threadIdx.x;
  const int lane = tid & 63;
  const int wv   = tid >> 6;
  const int wl   = lane & 15;
  const int q    = lane >> 4;
  floatx4 acc[4][4];
#pragma unroll
  for (int zi = 0; zi < 4; ++zi)
#pragma unroll
    for (int mi = 0; mi < 4; ++mi)
      acc[zi][mi] = (floatx4)0.0f;
  const float* xb = x + (size_t)b * 64 * 65536;
  for (int dt = 0; dt < 3; ++dt){
    const int tt = (t + dt + 15) & 15;
    for (int dy = 0; dy < 3; ++dy){
      const int yy = (y + dy + 15) & 15;
      __syncthreads();
      {
        const float* src = xb + tt*4096 + yy*256 + tid;
#pragma unroll
        for (int oct = 0; oct < 8; ++oct){
          float v[8];
#pragma unroll
          for (int j = 0; j < 8; ++j)
            v[j] = src[(size_t)(oct*8 + j) * 65536];
          short8 vv;
#pragma unroll
          for (int j = 0; j < 8; ++j) vv[j] = (short)f2bf(v[j]);
          *(short8*)(x_lds + tid*72 + oct*8) = vv;
        }
      }
      for (int dz = 0; dz < 3; ++dz){
        const int tap0 = ((dt*3 + dy)*3 + dz)*3;
        __syncthreads();
        {
          const u16* asrc = wp + (size_t)tap0 * 4096;
#pragma unroll
          for (int i = 0; i < 6; ++i){
            int e = (i*256 + tid) * 8;
            *(short8*)(a_lds + e) = *(const short8*)(asrc + e);
          }
        }
        __syncthreads();
#pragma unroll
        for (int dw = 0; dw < 3; ++dw){
          const int ww = (wl + dw + 15) & 15;
#pragma unroll
          for (int kc = 0; kc < 2; ++kc){
            bf16x8 af[4];
#pragma unroll
            for (int mi = 0; mi < 4; ++mi)
              af[mi] = *(const bf16x8*)(a_lds + ((dw*2 + kc)*64 + mi*16 + wl)*32 + q*8);
#pragma unroll
            for (int zi = 0; zi < 4; ++zi){
              const int zz = (wv*4 + zi + dz + 15) & 15;
              bf16x8 bf = *(const bf16x8*)(x_lds + (zz*16 + ww)*72 + kc*32 + q*8);
#pragma unroll
              for (int mi = 0; mi < 4; ++mi)
                acc[zi][mi] = __builtin_amdgcn_mfma_f32_16x16x32_bf16(af[mi], bf, acc[zi][mi], 0, 0, 0);
            }
          }
        }
      }
    }
  }
  float bvals[4][4];
#pragma unroll
  for (int mi = 0; mi < 4; ++mi)
#pragma unroll
    for (int r = 0; r < 4; ++r)
      bvals[mi][r] = bias[mi*16 + q*4 + r];
  float* ob = out + (size_t)b * 64 * 65536 + t*4096 + y*256 + wl;
#pragma unroll
  for (int zi = 0; zi < 4; ++zi){
    const int z = wv*4 + zi;
#pragma unroll
    for (int mi = 0; mi < 4; ++mi){
#pragma unroll
      for (int r = 0; r < 4; ++r){
        const int co = mi*16 + q*4 + r;
        ob[(size_t)co*65536 + z*16] = acc[zi][mi][r] + bvals[mi][r];
      }
    }
  }
}

extern "C" void kernel_launch(void* const* d_in, const int* in_sizes, int n_in,
                              void* d_out, int out_size, void* d_ws, size_t ws_size,
                              hipStream_t stream) {
  const float* x    = (const float*)d_in[0];
  const float* w    = (const float*)d_in[1];
  const float* bias = (const float*)d_in[2];
  float* out = (float*)d_out;

  const size_t xp_bytes = (size_t)1024 * 16384 * 2;   // 33.55 MB bf16 transposed x
  const size_t wp_bytes = 81*64*64*2;                  // 663.5 KB packed weights
  if (ws_size >= xp_bytes + wp_bytes){
    u16* xp = (u16*)d_ws;
    u16* wp = (u16*)((char*)d_ws + xp_bytes);
    prep_kernel<<<1024 + 1296, 256, 0, stream>>>(x, w, xp, wp);
    conv4d_mfma_v8<<<1024, 256, 0, stream>>>(xp, wp, bias, out);
  } else {
    u16* wp = (u16*)d_ws;
    repack_w_kernel<<<1296, 256, 0, stream>>>(w, wp);
    conv4d_mfma_kernel<<<1024, 256, 0, stream>>>(x, wp, bias, out);
  }
}